// Round 5
// baseline (3409.056 us; speedup 1.0000x reference)
//
#include <hip/hip_runtime.h>
#include <stdint.h>
#include <math.h>

typedef _Float16 half_t;
typedef _Float16 f16x8 __attribute__((ext_vector_type(8)));
typedef float f32x4 __attribute__((ext_vector_type(4)));

#define SLOPE 0.01f

__device__ inline float leaky(float v) { return v > 0.f ? v : SLOPE * v; }

__device__ inline void stage16(const half_t* g, half_t* l) {
    __builtin_amdgcn_global_load_lds(
        (const __attribute__((address_space(1))) unsigned int*)g,
        (__attribute__((address_space(3))) unsigned int*)l, 16, 0, 0);
}

__device__ inline float softplusf(float v) {
    return v > 20.f ? v : log1pf(expf(v));
}

// ---------------------------------------------------------------------------
// Weight prep: cast/reorder conv weights to oc-major fp16 ("B^T" GEMM operand)
// ---------------------------------------------------------------------------
__global__ void prep_kernel(const float* __restrict__ W1, const float* __restrict__ W2,
                            const float* __restrict__ W3,
                            half_t* __restrict__ B1w, half_t* __restrict__ B2w,
                            half_t* __restrict__ B3w)
{
    const unsigned idx = blockIdx.x * 256u + threadIdx.x;
    const unsigned n2 = 768u * 6912u;                 // 5,308,416
    if (idx < n2) {
        unsigned oc = idx / 6912u;
        unsigned rem = idx - oc * 6912u;
        unsigned tap = rem / 768u;
        unsigned ic = rem - tap * 768u;
        unsigned ky = tap / 3u, kx = tap - ky * 3u;
        B2w[idx] = (half_t)W2[(((size_t)oc * 768u + ic) * 3u + ky) * 3u + kx];
    } else if (idx < n2 + 147456u) {
        unsigned i = idx - n2;
        B1w[i] = (half_t)W1[i];                       // W1 flat is already (oc,ic)
    } else if (idx < n2 + 294912u) {
        unsigned i = idx - n2 - 147456u;
        B3w[i] = (half_t)W3[i];                       // W3 flat is already (oc,ic)
    }
}

// ---------------------------------------------------------------------------
// Per-window linear attention. One block per window. Writes feat NHWC fp16.
// ---------------------------------------------------------------------------
__global__ __launch_bounds__(256, 2)
void attn_kernel(const float* __restrict__ x,
                 const float* __restrict__ Wq, const float* __restrict__ bq,
                 const float* __restrict__ Wk, const float* __restrict__ bk,
                 const float* __restrict__ Wv, const float* __restrict__ bv,
                 const float* __restrict__ Wo, const float* __restrict__ bo,
                 half_t* __restrict__ featN)
{
    __shared__ half_t xls[192 * 65];
    __shared__ float wqL[512], wkL[512], wvL[512], woL[512];
    __shared__ float bqL[8], bkL[8], bvL[8], boL[64];
    __shared__ float kls[192 * 9], vls[192 * 9];
    __shared__ float sls[64];

    const int t = threadIdx.x;
    const int blk = blockIdx.x;
    const int b = blk >> 10;
    const int n = blk & 1023;
    const int wi = n >> 5, wj = n & 31;

    for (int i = t; i < 512; i += 256) {
        wqL[i] = Wq[i]; wkL[i] = Wk[i]; wvL[i] = Wv[i]; woL[i] = Wo[i];
    }
    if (t < 8)  { bqL[t] = bq[t]; bkL[t] = bk[t]; bvL[t] = bv[t]; }
    if (t < 64) boL[t] = bo[t];

    #pragma unroll
    for (int i = 0; i < 6; ++i) {
        int idx = t + i * 256;                 // 0..1535 = (c,py)
        int c = idx >> 3, py = idx & 7;
        const float* src = x + (((size_t)b * 192 + c) * 256 + (wi * 8 + py)) * 256 + wj * 8;
        float4 v0 = *(const float4*)src;
        float4 v1 = *(const float4*)(src + 4);
        half_t* dst = &xls[c * 65 + py * 8];
        dst[0] = (half_t)v0.x; dst[1] = (half_t)v0.y; dst[2] = (half_t)v0.z; dst[3] = (half_t)v0.w;
        dst[4] = (half_t)v1.x; dst[5] = (half_t)v1.y; dst[6] = (half_t)v1.z; dst[7] = (half_t)v1.w;
    }
    __syncthreads();

    float qf[8], kf[8], vf[8];
    if (t < 192) {
        #pragma unroll
        for (int d = 0; d < 8; ++d) { qf[d] = bqL[d]; kf[d] = bkL[d]; vf[d] = bvL[d]; }
        const half_t* xr = &xls[t * 65];
        for (int p = 0; p < 64; ++p) {
            float xv = (float)xr[p];
            const float* wqp = &wqL[p * 8];
            const float* wkp = &wkL[p * 8];
            const float* wvp = &wvL[p * 8];
            #pragma unroll
            for (int d = 0; d < 8; ++d) {
                qf[d] += xv * wqp[d];
                kf[d] += xv * wkp[d];
                vf[d] += xv * wvp[d];
            }
        }
        #pragma unroll
        for (int d = 0; d < 8; ++d) {
            qf[d] = softplusf(qf[d]);
            kf[d] = softplusf(kf[d]);
            kls[t * 9 + d] = kf[d];
            vls[t * 9 + d] = vf[d];
        }
    }
    __syncthreads();
    if (t < 64) {
        int e = t >> 3, dd = t & 7;
        float s = 0.f;
        for (int c = 0; c < 192; ++c) s += kls[c * 9 + e] * vls[c * 9 + dd];
        sls[t] = s;
    }
    __syncthreads();
    if (t < 192) {
        float rf[8];
        #pragma unroll
        for (int d = 0; d < 8; ++d) {
            float s = 0.f;
            #pragma unroll
            for (int e = 0; e < 8; ++e) s += qf[e] * sls[e * 8 + d];
            rf[d] = s;
        }
        half_t* xr = &xls[t * 65];
        for (int p = 0; p < 64; ++p) {
            float a = boL[p];
            #pragma unroll
            for (int d = 0; d < 8; ++d) a += rf[d] * woL[d * 64 + p];
            xr[p] = (half_t)((float)xr[p] + a);
        }
    }
    __syncthreads();
    half_t* dst = featN + ((size_t)b * 65536 + (size_t)n * 64) * 192;
    for (int i = 0; i < 48; ++i) {
        int idx = t + i * 256;                 // 0..12287 = p*192 + c
        int p = idx / 192, c = idx - p * 192;
        dst[idx] = xls[c * 65 + p];
    }
}

// ---------------------------------------------------------------------------
// conv1: 1x1 192->768 + leaky. GEMM M=65536 (one batch), N=768, K=192.
// ---------------------------------------------------------------------------
__global__ __launch_bounds__(256, 2)
void conv1_kernel(const half_t* __restrict__ featN, const half_t* __restrict__ B1w,
                  const float* __restrict__ b1, half_t* __restrict__ h1p, int batch)
{
    __shared__ half_t As[128 * 64];
    __shared__ half_t Bs[128 * 64];
    const int t = threadIdx.x;
    const int lane = t & 63;
    const int w = t >> 6;
    const int m0 = blockIdx.x * 128;
    const int n0 = blockIdx.y * 128;
    const int wm = (w >> 1) * 64, wn = (w & 1) * 64;
    const int rbase = t >> 3;
    const int g = (t & 7) ^ (rbase & 7);
    const int ar = lane & 15, kc = lane >> 4;

    f32x4 acc[4][4];
    #pragma unroll
    for (int i = 0; i < 4; ++i)
        #pragma unroll
        for (int j = 0; j < 4; ++j) acc[i][j] = (f32x4){0.f, 0.f, 0.f, 0.f};

    const size_t mb = (size_t)batch * 65536 + m0;

    for (int s = 0; s < 3; ++s) {
        const int k0 = s * 64;
        const half_t* ga = featN + (mb + rbase) * 192 + k0 + g * 8;
        const half_t* gb = B1w + (size_t)(n0 + rbase) * 192 + k0 + g * 8;
        half_t* la = As + t * 8;
        half_t* lb = Bs + t * 8;
        #pragma unroll
        for (int i = 0; i < 4; ++i) {
            stage16(ga + (size_t)32 * i * 192, la + 2048 * i);
            stage16(gb + (size_t)32 * i * 192, lb + 2048 * i);
        }
        __syncthreads();
        #pragma unroll
        for (int kh = 0; kh < 2; ++kh) {
            f16x8 af[4], bfr[4];
            const int c = kh * 4 + kc;
            #pragma unroll
            for (int mf = 0; mf < 4; ++mf) {
                int r = wm + mf * 16 + ar;
                af[mf] = *(const f16x8*)&As[(r * 8 + (c ^ (r & 7))) * 8];
            }
            #pragma unroll
            for (int nf = 0; nf < 4; ++nf) {
                int r = wn + nf * 16 + ar;
                bfr[nf] = *(const f16x8*)&Bs[(r * 8 + (c ^ (r & 7))) * 8];
            }
            #pragma unroll
            for (int mf = 0; mf < 4; ++mf)
                #pragma unroll
                for (int nf = 0; nf < 4; ++nf)
                    acc[mf][nf] = __builtin_amdgcn_mfma_f32_16x16x32_f16(af[mf], bfr[nf], acc[mf][nf], 0, 0, 0);
        }
        __syncthreads();
    }

    const int y = m0 >> 8, x0 = m0 & 255;
    half_t* outrow = h1p + ((size_t)(y + 1) * 258 + (x0 + 1)) * 768;
    #pragma unroll
    for (int nf = 0; nf < 4; ++nf) {
        int n = n0 + wn + nf * 16 + ar;
        float bias = b1[n];
        #pragma unroll
        for (int mf = 0; mf < 4; ++mf) {
            #pragma unroll
            for (int r4 = 0; r4 < 4; ++r4) {
                int local = wm + mf * 16 + kc * 4 + r4;
                outrow[(size_t)local * 768 + n] = (half_t)leaky(acc[mf][nf][r4] + bias);
            }
        }
    }
}

// ---------------------------------------------------------------------------
// conv2 v5: 3x3 SAME 768->768 + leaky, implicit GEMM, 256x256 tile, BK=64,
// 8-phase with full read-ahead AND pre-MFMA cross-buffer prefetch:
// q0 B-fragments ping-pong between bf0A/bf0B so the next-buffer reads at
// ph4/ph8 can issue BEFORE the MFMA cluster (no register WAR), giving every
// lgkm wait >=1 MFMA cluster of slack. 8 barriers/iter (ph4/ph8 have none
// trailing: ph6/ph2 stages are ordered behind ph5/ph1's LGKM+SBAR).
// Waits/half-iter: LGKM(4), LGKM(8), LGKM(0), VMC(8). Never vmcnt(0) steady.
// Grid: nt-grouped so the 32 co-resident blocks/XCD share one B-panel (L2).
// ---------------------------------------------------------------------------
__device__ __forceinline__ void c2_stage_A(half_t* As, int buf, int h,
    const half_t* __restrict__ h1p, int y, int kstep, int t, int cg)
{
    const int tap = kstep / 12, icc = kstep - tap * 12;
    const int ky = tap / 3, kx = tap - ky * 3;
    const int row0 = t >> 3;
    const half_t* g = h1p + ((size_t)(y + ky) * 258 + (kx + h * 128 + row0)) * 768
                      + icc * 64 + cg;
    half_t* l = As + (buf * 2 + h) * 8192 + t * 8;
    stage16(g, l);
    stage16(g + (size_t)64 * 768, l + 4096);
}

__device__ __forceinline__ void c2_stage_B(half_t* Bs, int buf, int h,
    const half_t* __restrict__ B2w, int n0, int kstep, int t, int cg)
{
    const int tap = kstep / 12, icc = kstep - tap * 12;
    const int row0 = t >> 3;
    const half_t* g = B2w + (size_t)(n0 + h * 128 + row0) * 6912
                      + tap * 768 + icc * 64 + cg;
    half_t* l = Bs + (buf * 2 + h) * 8192 + t * 8;
    stage16(g, l);
    stage16(g + (size_t)64 * 6912, l + 4096);
}

#define SBAR __builtin_amdgcn_s_barrier()
#define SB0  __builtin_amdgcn_sched_barrier(0)
#define LGKM(N) asm volatile("s_waitcnt lgkmcnt(" #N ")" ::: "memory")
#define VMC(N)  asm volatile("s_waitcnt vmcnt(" #N ")" ::: "memory")

// 8 ds_read_b128 into af[MQ]
#define RDA(MQ, BUF)                                                             \
  _Pragma("unroll")                                                              \
  for (int mf = 0; mf < 4; ++mf)                                                 \
    _Pragma("unroll")                                                            \
    for (int kh = 0; kh < 2; ++kh) {                                             \
      const int lr = wm * 64 + mf * 16 + ar;                                     \
      const int ch = (kh * 4 + kc) ^ (lr & 7);                                   \
      af[MQ][mf][kh] = *(const f16x8*)&As[((BUF)*2 + (MQ))*8192 + lr*64 + ch*8]; \
    }

// 4 ds_read_b128 into named B-frag register set REG, from Bs half NQ
#define RDBX(REG, NQ, BUF)                                                       \
  _Pragma("unroll")                                                              \
  for (int nf = 0; nf < 2; ++nf)                                                 \
    _Pragma("unroll")                                                            \
    for (int kh = 0; kh < 2; ++kh) {                                             \
      const int lc = wn * 32 + nf * 16 + ar;                                     \
      const int ch = (kh * 4 + kc) ^ (lc & 7);                                   \
      REG[nf][kh] = *(const f16x8*)&Bs[((BUF)*2 + (NQ))*8192 + lc*64 + ch*8];    \
    }

#define MMA16X(MQ, NQ, BREG)                                                     \
  {                                                                              \
    __builtin_amdgcn_s_setprio(1);                                               \
    _Pragma("unroll")                                                            \
    for (int kh = 0; kh < 2; ++kh)                                               \
      _Pragma("unroll")                                                          \
      for (int mf = 0; mf < 4; ++mf)                                             \
        _Pragma("unroll")                                                        \
        for (int nf = 0; nf < 2; ++nf)                                           \
          acc[(MQ)*2+(NQ)][mf][nf] = __builtin_amdgcn_mfma_f32_16x16x32_f16(     \
              af[MQ][mf][kh], BREG[nf][kh], acc[(MQ)*2+(NQ)][mf][nf], 0, 0, 0);  \
    __builtin_amdgcn_s_setprio(0);                                               \
  }

__global__ __launch_bounds__(512, 2)
void conv2_kernel(const half_t* __restrict__ h1p, const half_t* __restrict__ B2w,
                  const float* __restrict__ b2, half_t* __restrict__ h2)
{
    __shared__ half_t As[4 * 8192];    // [buf][half][128][64] f16 = 64 KiB
    __shared__ half_t Bs[4 * 8192];

    const int t = threadIdx.x;
    const int lane = t & 63;
    const int w = t >> 6;
    const int wm = w >> 2, wn = w & 3;            // 2x4 wave grid inside a quadrant
    const int ar = lane & 15, kc = lane >> 4;
    const int cg = (((t & 7) ^ ((t >> 3) & 7)) << 3);  // pre-swizzled source chunk

    // nt-grouped XCD swizzle: the 32 co-resident blocks per XCD share ONE
    // B-panel (3.54 MB, L2-fits) and own contiguous y-bands for A-halo reuse.
    const int bid = blockIdx.x;
    const int xcd = bid & 7, sid = bid >> 3;      // 96 blocks per XCD
    const int nt = sid >> 5;                       // 0..2
    const int mtile = xcd * 32 + (sid & 31);       // y-band per XCD
    const int y = mtile;
    const int m0 = mtile * 256;
    const int n0 = nt * 256;

    f32x4 acc[4][4][2];
    #pragma unroll
    for (int q = 0; q < 4; ++q)
        #pragma unroll
        for (int i = 0; i < 4; ++i)
            #pragma unroll
            for (int j = 0; j < 2; ++j) acc[q][i][j] = (f32x4){0.f, 0.f, 0.f, 0.f};

    f16x8 af[2][4][2];     // [MQ][mf][kh]
    f16x8 bf1[2][2];       // q1 B-frags (re-read every half-iter)
    f16x8 bf0A[2][2];      // q0 B-frags, buffer-0 ping
    f16x8 bf0B[2][2];      // q0 B-frags, buffer-1 pong

    // Prologue: stage buf0<-k0 (8 loads), buf1<-k1 (8 loads); wait buf0 only.
    c2_stage_A(As, 0, 0, h1p, y, 0, t, cg);
    c2_stage_A(As, 0, 1, h1p, y, 0, t, cg);
    c2_stage_B(Bs, 0, 0, B2w, n0, 0, t, cg);
    c2_stage_B(Bs, 0, 1, B2w, n0, 0, t, cg);
    c2_stage_A(As, 1, 0, h1p, y, 1, t, cg);
    c2_stage_A(As, 1, 1, h1p, y, 1, t, cg);
    c2_stage_B(Bs, 1, 0, B2w, n0, 1, t, cg);
    c2_stage_B(Bs, 1, 1, B2w, n0, 1, t, cg);
    VMC(8);
    SBAR; SB0;
    RDBX(bf0A, 0, 0); SB0;
    RDA(0, 0);

    // Steady: 53 iterations (compute kt 0..105; stage up to kt 107).
    for (int i = 0; i < 53; ++i) {
        const int k2 = 2 * i + 2;
        const int k3 = 2 * i + 3;
        // ph1 (q00 buf0)
        RDBX(bf1, 1, 0);
        LGKM(4); SB0;
        MMA16X(0, 0, bf0A);
        SBAR;
        // ph2 (q01 buf0): stage A0h0,B0h0 <- k2
        c2_stage_A(As, 0, 0, h1p, y, k2, t, cg);
        c2_stage_B(Bs, 0, 0, B2w, n0, k2, t, cg);
        RDA(1, 0);
        LGKM(8); SB0;
        MMA16X(0, 1, bf1);
        SBAR;
        // ph3 (q11 buf0)
        LGKM(0); SB0;
        MMA16X(1, 1, bf1);
        SBAR;
        // ph4 (q10 buf0): stage A0h1,B0h1 <- k2; prefetch buf1 q0 frags PRE-MFMA
        c2_stage_A(As, 0, 1, h1p, y, k2, t, cg);
        c2_stage_B(Bs, 0, 1, B2w, n0, k2, t, cg);
        VMC(8);
        SBAR; SB0;
        RDA(0, 1);
        RDBX(bf0B, 0, 1); SB0;
        MMA16X(1, 0, bf0A);
        // (no barrier: ph6's stage is ordered behind ph5's LGKM+SBAR)
        // ph5 (q00 buf1)
        RDBX(bf1, 1, 1);
        LGKM(4); SB0;
        MMA16X(0, 0, bf0B);
        SBAR;
        // ph6 (q01 buf1): stage A1h0,B1h0 <- k3
        c2_stage_A(As, 1, 0, h1p, y, k3, t, cg);
        c2_stage_B(Bs, 1, 0, B2w, n0, k3, t, cg);
        RDA(1, 1);
        LGKM(8); SB0;
        MMA16X(0, 1, bf1);
        SBAR;
        // ph7 (q11 buf1)
        LGKM(0); SB0;
        MMA16X(1, 1, bf1);
        SBAR;
        // ph8 (q10 buf1): stage A1h1,B1h1 <- k3; prefetch buf0 q0 frags PRE-MFMA
        c2_stage_A(As, 1, 1, h1p, y, k3, t, cg);
        c2_stage_B(Bs, 1, 1, B2w, n0, k3, t, cg);
        VMC(8);
        SBAR; SB0;
        RDA(0, 0);
        RDBX(bf0A, 0, 0); SB0;
        MMA16X(1, 0, bf0B);
    }
    // Tail: kt 106 (buf0), 107 (buf1); no stages, drain once.
    {
        RDBX(bf1, 1, 0);
        LGKM(4); SB0;
        MMA16X(0, 0, bf0A);
        SBAR;
        RDA(1, 0);
        LGKM(8); SB0;
        MMA16X(0, 1, bf1);
        SBAR;
        LGKM(0); SB0;
        MMA16X(1, 1, bf1);
        SBAR;
        VMC(0);
        SBAR; SB0;
        RDA(0, 1);
        RDBX(bf0B, 0, 1); SB0;
        MMA16X(1, 0, bf0A);
        RDBX(bf1, 1, 1);
        LGKM(4); SB0;
        MMA16X(0, 0, bf0B);
        SBAR;
        RDA(1, 1);
        LGKM(8); SB0;
        MMA16X(0, 1, bf1);
        SBAR;
        LGKM(0); SB0;
        MMA16X(1, 1, bf1);
        SBAR;
        MMA16X(1, 0, bf0B);
    }

    // Epilogue: bias + leaky, write NHWC fp16.
    #pragma unroll
    for (int q = 0; q < 4; ++q) {
        const int mq = q >> 1, nq = q & 1;
        #pragma unroll
        for (int nf = 0; nf < 2; ++nf) {
            const int col = n0 + nq * 128 + wn * 32 + nf * 16 + ar;
            const float bias = b2[col];
            #pragma unroll
            for (int mf = 0; mf < 4; ++mf) {
                const int row = m0 + mq * 128 + wm * 64 + mf * 16 + kc * 4;
                half_t* op = h2 + (size_t)row * 768 + col;
                #pragma unroll
                for (int r4 = 0; r4 < 4; ++r4)
                    op[(size_t)r4 * 768] = (half_t)leaky(acc[q][mf][nf][r4] + bias);
            }
        }
    }
}

// ---------------------------------------------------------------------------
// conv3: 1x1 768->192 + leaky. GEMM M=65536 (one batch), N=192, K=768.
// ---------------------------------------------------------------------------
__global__ __launch_bounds__(256, 2)
void conv3_kernel(const half_t* __restrict__ h2, const half_t* __restrict__ B3w,
                  const float* __restrict__ b3, float* __restrict__ out, int batch)
{
    __shared__ half_t As[128 * 64];
    __shared__ half_t Bs[192 * 64];
    const int t = threadIdx.x;
    const int lane = t & 63;
    const int w = t >> 6;
    const int m0 = blockIdx.x * 128;
    const int wm = (w >> 1) * 64;
    const int wn = (w & 1) * 96;
    const int rbase = t >> 3;
    const int g = (t & 7) ^ (rbase & 7);
    const int ar = lane & 15, kc = lane >> 4;

    f32x4 acc[4][6];
    #pragma unroll
    for (int i = 0; i < 4; ++i)
        #pragma unroll
        for (int j = 0; j < 6; ++j) acc[i][j] = (f32x4){0.f, 0.f, 0.f, 0.f};

    for (int s = 0; s < 12; ++s) {
        const int k0 = s * 64;
        const half_t* ga = h2 + (size_t)(m0 + rbase) * 768 + k0 + g * 8;
        const half_t* gb = B3w + (size_t)rbase * 768 + k0 + g * 8;
        half_t* la = As + t * 8;
        half_t* lb = Bs + t * 8;
        #pragma unroll
        for (int i = 0; i < 4; ++i) stage16(ga + (size_t)32 * i * 768, la + 2048 * i);
        #pragma unroll
        for (int i = 0; i < 6; ++i) stage16(gb + (size_t)32 * i * 768, lb + 2048 * i);
        __syncthreads();
        #pragma unroll
        for (int kh = 0; kh < 2; ++kh) {
            f16x8 af[4], bfr[6];
            const int c = kh * 4 + kc;
            #pragma unroll
            for (int mf = 0; mf < 4; ++mf) {
                int r = wm + mf * 16 + ar;
                af[mf] = *(const f16x8*)&As[(r * 8 + (c ^ (r & 7))) * 8];
            }
            #pragma unroll
            for (int nf = 0; nf < 6; ++nf) {
                int r = wn + nf * 16 + ar;
                bfr[nf] = *(const f16x8*)&Bs[(r * 8 + (c ^ (r & 7))) * 8];
            }
            #pragma unroll
            for (int mf = 0; mf < 4; ++mf)
                #pragma unroll
                for (int nf = 0; nf < 6; ++nf)
                    acc[mf][nf] = __builtin_amdgcn_mfma_f32_16x16x32_f16(af[mf], bfr[nf], acc[mf][nf], 0, 0, 0);
        }
        __syncthreads();
    }

    #pragma unroll
    for (int nf = 0; nf < 6; ++nf) {
        int n = wn + nf * 16 + ar;
        float bias = b3[n];
        float* op = out + ((size_t)batch * 192 + n) * 65536 + m0;
        #pragma unroll
        for (int mf = 0; mf < 4; ++mf) {
            int local = wm + mf * 16 + kc * 4;
            f32x4 v;
            #pragma unroll
            for (int r4 = 0; r4 < 4; ++r4) v[r4] = leaky(acc[mf][nf][r4] + bias);
            *(f32x4*)(op + local) = v;
        }
    }
}

// ---------------------------------------------------------------------------
extern "C" void kernel_launch(void* const* d_in, const int* in_sizes, int n_in,
                              void* d_out, int out_size, void* d_ws, size_t ws_size,
                              hipStream_t stream)
{
    const float* x  = (const float*)d_in[0];
    const float* Wq = (const float*)d_in[1];
    const float* bq = (const float*)d_in[2];
    const float* Wk = (const float*)d_in[3];
    const float* bk = (const float*)d_in[4];
    const float* Wv = (const float*)d_in[5];
    const float* bv = (const float*)d_in[6];
    const float* Wo = (const float*)d_in[7];
    const float* bo = (const float*)d_in[8];
    const float* W1 = (const float*)d_in[9];
    const float* b1 = (const float*)d_in[10];
    const float* W2 = (const float*)d_in[11];
    const float* b2 = (const float*)d_in[12];
    const float* W3 = (const float*)d_in[13];
    const float* b3 = (const float*)d_in[14];

    char* ws = (char*)d_ws;
    const size_t OFF_B1   = 0;
    const size_t OFF_B3   = 294912;
    const size_t OFF_B2   = 589824;
    const size_t OFF_FEAT = 11206656;
    const size_t OFF_H1P  = 111869952;
    const size_t OFF_H2   = 214124544;
    const size_t WS_NEED  = 314787840;
    if (ws_size < WS_NEED) return;

    half_t* B1w   = (half_t*)(ws + OFF_B1);
    half_t* B3w   = (half_t*)(ws + OFF_B3);
    half_t* B2w   = (half_t*)(ws + OFF_B2);
    half_t* featN = (half_t*)(ws + OFF_FEAT);
    half_t* h1p   = (half_t*)(ws + OFF_H1P);
    half_t* h2    = (half_t*)(ws + OFF_H2);

    hipMemsetAsync(h1p, 0, 102254592, stream);
    prep_kernel<<<21888, 256, 0, stream>>>(W1, W2, W3, B1w, B2w, B3w);
    attn_kernel<<<4096, 256, 0, stream>>>(x, Wq, bq, Wk, bk, Wv, bv, Wo, bo, featN);

    for (int b = 0; b < 4; ++b) {
        conv1_kernel<<<dim3(512, 6), 256, 0, stream>>>(featN, B1w, b1, h1p, b);
        conv2_kernel<<<768, 512, 0, stream>>>(h1p, B2w, b2, h2);
        conv3_kernel<<<dim3(512, 1), 256, 0, stream>>>(h2, B3w, b3, (float*)d_out, b);
    }
}

// Round 6
// 3053.588 us; speedup vs baseline: 1.1164x; 1.1164x over previous
//
#include <hip/hip_runtime.h>
#include <stdint.h>
#include <math.h>

typedef _Float16 half_t;
typedef _Float16 f16x8 __attribute__((ext_vector_type(8)));
typedef float f32x4 __attribute__((ext_vector_type(4)));

#define SLOPE 0.01f

__device__ inline float leaky(float v) { return v > 0.f ? v : SLOPE * v; }

__device__ inline void stage16(const half_t* g, half_t* l) {
    __builtin_amdgcn_global_load_lds(
        (const __attribute__((address_space(1))) unsigned int*)g,
        (__attribute__((address_space(3))) unsigned int*)l, 16, 0, 0);
}

__device__ inline float softplusf(float v) {
    return v > 20.f ? v : log1pf(expf(v));
}

// ---------------------------------------------------------------------------
// Weight prep: cast/reorder conv weights to oc-major fp16 ("B^T" GEMM operand)
// ---------------------------------------------------------------------------
__global__ void prep_kernel(const float* __restrict__ W1, const float* __restrict__ W2,
                            const float* __restrict__ W3,
                            half_t* __restrict__ B1w, half_t* __restrict__ B2w,
                            half_t* __restrict__ B3w)
{
    const unsigned idx = blockIdx.x * 256u + threadIdx.x;
    const unsigned n2 = 768u * 6912u;                 // 5,308,416
    if (idx < n2) {
        unsigned oc = idx / 6912u;
        unsigned rem = idx - oc * 6912u;
        unsigned tap = rem / 768u;
        unsigned ic = rem - tap * 768u;
        unsigned ky = tap / 3u, kx = tap - ky * 3u;
        B2w[idx] = (half_t)W2[(((size_t)oc * 768u + ic) * 3u + ky) * 3u + kx];
    } else if (idx < n2 + 147456u) {
        unsigned i = idx - n2;
        B1w[i] = (half_t)W1[i];                       // W1 flat is already (oc,ic)
    } else if (idx < n2 + 294912u) {
        unsigned i = idx - n2 - 147456u;
        B3w[i] = (half_t)W3[i];                       // W3 flat is already (oc,ic)
    }
}

// ---------------------------------------------------------------------------
// Per-window linear attention. One block per window. Writes feat NHWC fp16.
// ---------------------------------------------------------------------------
__global__ __launch_bounds__(256, 2)
void attn_kernel(const float* __restrict__ x,
                 const float* __restrict__ Wq, const float* __restrict__ bq,
                 const float* __restrict__ Wk, const float* __restrict__ bk,
                 const float* __restrict__ Wv, const float* __restrict__ bv,
                 const float* __restrict__ Wo, const float* __restrict__ bo,
                 half_t* __restrict__ featN)
{
    __shared__ half_t xls[192 * 65];
    __shared__ float wqL[512], wkL[512], wvL[512], woL[512];
    __shared__ float bqL[8], bkL[8], bvL[8], boL[64];
    __shared__ float kls[192 * 9], vls[192 * 9];
    __shared__ float sls[64];

    const int t = threadIdx.x;
    const int blk = blockIdx.x;
    const int b = blk >> 10;
    const int n = blk & 1023;
    const int wi = n >> 5, wj = n & 31;

    for (int i = t; i < 512; i += 256) {
        wqL[i] = Wq[i]; wkL[i] = Wk[i]; wvL[i] = Wv[i]; woL[i] = Wo[i];
    }
    if (t < 8)  { bqL[t] = bq[t]; bkL[t] = bk[t]; bvL[t] = bv[t]; }
    if (t < 64) boL[t] = bo[t];

    #pragma unroll
    for (int i = 0; i < 6; ++i) {
        int idx = t + i * 256;                 // 0..1535 = (c,py)
        int c = idx >> 3, py = idx & 7;
        const float* src = x + (((size_t)b * 192 + c) * 256 + (wi * 8 + py)) * 256 + wj * 8;
        float4 v0 = *(const float4*)src;
        float4 v1 = *(const float4*)(src + 4);
        half_t* dst = &xls[c * 65 + py * 8];
        dst[0] = (half_t)v0.x; dst[1] = (half_t)v0.y; dst[2] = (half_t)v0.z; dst[3] = (half_t)v0.w;
        dst[4] = (half_t)v1.x; dst[5] = (half_t)v1.y; dst[6] = (half_t)v1.z; dst[7] = (half_t)v1.w;
    }
    __syncthreads();

    float qf[8], kf[8], vf[8];
    if (t < 192) {
        #pragma unroll
        for (int d = 0; d < 8; ++d) { qf[d] = bqL[d]; kf[d] = bkL[d]; vf[d] = bvL[d]; }
        const half_t* xr = &xls[t * 65];
        for (int p = 0; p < 64; ++p) {
            float xv = (float)xr[p];
            const float* wqp = &wqL[p * 8];
            const float* wkp = &wkL[p * 8];
            const float* wvp = &wvL[p * 8];
            #pragma unroll
            for (int d = 0; d < 8; ++d) {
                qf[d] += xv * wqp[d];
                kf[d] += xv * wkp[d];
                vf[d] += xv * wvp[d];
            }
        }
        #pragma unroll
        for (int d = 0; d < 8; ++d) {
            qf[d] = softplusf(qf[d]);
            kf[d] = softplusf(kf[d]);
            kls[t * 9 + d] = kf[d];
            vls[t * 9 + d] = vf[d];
        }
    }
    __syncthreads();
    if (t < 64) {
        int e = t >> 3, dd = t & 7;
        float s = 0.f;
        for (int c = 0; c < 192; ++c) s += kls[c * 9 + e] * vls[c * 9 + dd];
        sls[t] = s;
    }
    __syncthreads();
    if (t < 192) {
        float rf[8];
        #pragma unroll
        for (int d = 0; d < 8; ++d) {
            float s = 0.f;
            #pragma unroll
            for (int e = 0; e < 8; ++e) s += qf[e] * sls[e * 8 + d];
            rf[d] = s;
        }
        half_t* xr = &xls[t * 65];
        for (int p = 0; p < 64; ++p) {
            float a = boL[p];
            #pragma unroll
            for (int d = 0; d < 8; ++d) a += rf[d] * woL[d * 64 + p];
            xr[p] = (half_t)((float)xr[p] + a);
        }
    }
    __syncthreads();
    half_t* dst = featN + ((size_t)b * 65536 + (size_t)n * 64) * 192;
    for (int i = 0; i < 48; ++i) {
        int idx = t + i * 256;                 // 0..12287 = p*192 + c
        int p = idx / 192, c = idx - p * 192;
        dst[idx] = xls[c * 65 + p];
    }
}

// ---------------------------------------------------------------------------
// conv1: 1x1 192->768 + leaky. GEMM M=65536 (one batch), N=768, K=192.
// ---------------------------------------------------------------------------
__global__ __launch_bounds__(256, 2)
void conv1_kernel(const half_t* __restrict__ featN, const half_t* __restrict__ B1w,
                  const float* __restrict__ b1, half_t* __restrict__ h1p, int batch)
{
    __shared__ half_t As[128 * 64];
    __shared__ half_t Bs[128 * 64];
    const int t = threadIdx.x;
    const int lane = t & 63;
    const int w = t >> 6;
    const int m0 = blockIdx.x * 128;
    const int n0 = blockIdx.y * 128;
    const int wm = (w >> 1) * 64, wn = (w & 1) * 64;
    const int rbase = t >> 3;
    const int g = (t & 7) ^ (rbase & 7);
    const int ar = lane & 15, kc = lane >> 4;

    f32x4 acc[4][4];
    #pragma unroll
    for (int i = 0; i < 4; ++i)
        #pragma unroll
        for (int j = 0; j < 4; ++j) acc[i][j] = (f32x4){0.f, 0.f, 0.f, 0.f};

    const size_t mb = (size_t)batch * 65536 + m0;

    for (int s = 0; s < 3; ++s) {
        const int k0 = s * 64;
        const half_t* ga = featN + (mb + rbase) * 192 + k0 + g * 8;
        const half_t* gb = B1w + (size_t)(n0 + rbase) * 192 + k0 + g * 8;
        half_t* la = As + t * 8;
        half_t* lb = Bs + t * 8;
        #pragma unroll
        for (int i = 0; i < 4; ++i) {
            stage16(ga + (size_t)32 * i * 192, la + 2048 * i);
            stage16(gb + (size_t)32 * i * 192, lb + 2048 * i);
        }
        __syncthreads();
        #pragma unroll
        for (int kh = 0; kh < 2; ++kh) {
            f16x8 af[4], bfr[4];
            const int c = kh * 4 + kc;
            #pragma unroll
            for (int mf = 0; mf < 4; ++mf) {
                int r = wm + mf * 16 + ar;
                af[mf] = *(const f16x8*)&As[(r * 8 + (c ^ (r & 7))) * 8];
            }
            #pragma unroll
            for (int nf = 0; nf < 4; ++nf) {
                int r = wn + nf * 16 + ar;
                bfr[nf] = *(const f16x8*)&Bs[(r * 8 + (c ^ (r & 7))) * 8];
            }
            #pragma unroll
            for (int mf = 0; mf < 4; ++mf)
                #pragma unroll
                for (int nf = 0; nf < 4; ++nf)
                    acc[mf][nf] = __builtin_amdgcn_mfma_f32_16x16x32_f16(af[mf], bfr[nf], acc[mf][nf], 0, 0, 0);
        }
        __syncthreads();
    }

    const int y = m0 >> 8, x0 = m0 & 255;
    half_t* outrow = h1p + ((size_t)(y + 1) * 258 + (x0 + 1)) * 768;
    #pragma unroll
    for (int nf = 0; nf < 4; ++nf) {
        int n = n0 + wn + nf * 16 + ar;
        float bias = b1[n];
        #pragma unroll
        for (int mf = 0; mf < 4; ++mf) {
            #pragma unroll
            for (int r4 = 0; r4 < 4; ++r4) {
                int local = wm + mf * 16 + kc * 4 + r4;
                outrow[(size_t)local * 768 + n] = (half_t)leaky(acc[mf][nf][r4] + bias);
            }
        }
    }
}

// ---------------------------------------------------------------------------
// conv2 v6 = v5 schedule + v4 grid (single-variable revert of the r5 grid).
// 3x3 SAME 768->768 + leaky, implicit GEMM, 256x256 tile, BK=64, 8-phase,
// full read-ahead + pre-MFMA cross-buffer prefetch (bf0 ping-pong).
// Grid: nt innermost (3 nt-blocks per mtile share A rows instantaneously),
// XCD-chunked mtile bands — the round-4 mapping that measured FETCH=594MB.
// ---------------------------------------------------------------------------
__device__ __forceinline__ void c2_stage_A(half_t* As, int buf, int h,
    const half_t* __restrict__ h1p, int y, int kstep, int t, int cg)
{
    const int tap = kstep / 12, icc = kstep - tap * 12;
    const int ky = tap / 3, kx = tap - ky * 3;
    const int row0 = t >> 3;
    const half_t* g = h1p + ((size_t)(y + ky) * 258 + (kx + h * 128 + row0)) * 768
                      + icc * 64 + cg;
    half_t* l = As + (buf * 2 + h) * 8192 + t * 8;
    stage16(g, l);
    stage16(g + (size_t)64 * 768, l + 4096);
}

__device__ __forceinline__ void c2_stage_B(half_t* Bs, int buf, int h,
    const half_t* __restrict__ B2w, int n0, int kstep, int t, int cg)
{
    const int tap = kstep / 12, icc = kstep - tap * 12;
    const int row0 = t >> 3;
    const half_t* g = B2w + (size_t)(n0 + h * 128 + row0) * 6912
                      + tap * 768 + icc * 64 + cg;
    half_t* l = Bs + (buf * 2 + h) * 8192 + t * 8;
    stage16(g, l);
    stage16(g + (size_t)64 * 6912, l + 4096);
}

#define SBAR __builtin_amdgcn_s_barrier()
#define SB0  __builtin_amdgcn_sched_barrier(0)
#define LGKM(N) asm volatile("s_waitcnt lgkmcnt(" #N ")" ::: "memory")
#define VMC(N)  asm volatile("s_waitcnt vmcnt(" #N ")" ::: "memory")

// 8 ds_read_b128 into af[MQ]
#define RDA(MQ, BUF)                                                             \
  _Pragma("unroll")                                                              \
  for (int mf = 0; mf < 4; ++mf)                                                 \
    _Pragma("unroll")                                                            \
    for (int kh = 0; kh < 2; ++kh) {                                             \
      const int lr = wm * 64 + mf * 16 + ar;                                     \
      const int ch = (kh * 4 + kc) ^ (lr & 7);                                   \
      af[MQ][mf][kh] = *(const f16x8*)&As[((BUF)*2 + (MQ))*8192 + lr*64 + ch*8]; \
    }

// 4 ds_read_b128 into named B-frag register set REG, from Bs half NQ
#define RDBX(REG, NQ, BUF)                                                       \
  _Pragma("unroll")                                                              \
  for (int nf = 0; nf < 2; ++nf)                                                 \
    _Pragma("unroll")                                                            \
    for (int kh = 0; kh < 2; ++kh) {                                             \
      const int lc = wn * 32 + nf * 16 + ar;                                     \
      const int ch = (kh * 4 + kc) ^ (lc & 7);                                   \
      REG[nf][kh] = *(const f16x8*)&Bs[((BUF)*2 + (NQ))*8192 + lc*64 + ch*8];    \
    }

#define MMA16X(MQ, NQ, BREG)                                                     \
  {                                                                              \
    __builtin_amdgcn_s_setprio(1);                                               \
    _Pragma("unroll")                                                            \
    for (int kh = 0; kh < 2; ++kh)                                               \
      _Pragma("unroll")                                                          \
      for (int mf = 0; mf < 4; ++mf)                                             \
        _Pragma("unroll")                                                        \
        for (int nf = 0; nf < 2; ++nf)                                           \
          acc[(MQ)*2+(NQ)][mf][nf] = __builtin_amdgcn_mfma_f32_16x16x32_f16(     \
              af[MQ][mf][kh], BREG[nf][kh], acc[(MQ)*2+(NQ)][mf][nf], 0, 0, 0);  \
    __builtin_amdgcn_s_setprio(0);                                               \
  }

__global__ __launch_bounds__(512, 2)
void conv2_kernel(const half_t* __restrict__ h1p, const half_t* __restrict__ B2w,
                  const float* __restrict__ b2, half_t* __restrict__ h2)
{
    __shared__ half_t As[4 * 8192];    // [buf][half][128][64] f16 = 64 KiB
    __shared__ half_t Bs[4 * 8192];

    const int t = threadIdx.x;
    const int lane = t & 63;
    const int w = t >> 6;
    const int wm = w >> 2, wn = w & 3;            // 2x4 wave grid inside a quadrant
    const int ar = lane & 15, kc = lane >> 4;
    const int cg = (((t & 7) ^ ((t >> 3) & 7)) << 3);  // pre-swizzled source chunk

    // Round-4 grid: nt innermost + XCD-chunked mtile bands.
    const int bid = blockIdx.x;
    const int xcd = bid & 7, sid = bid >> 3;      // 96 blocks per XCD
    const int wg = xcd * 96 + sid;                // 768 = 8 XCD * 96
    const int mtile = wg / 3;                     // = xcd*32 + sid/3
    const int nt = wg - mtile * 3;                // = sid % 3
    const int y = mtile;
    const int m0 = mtile * 256;
    const int n0 = nt * 256;

    f32x4 acc[4][4][2];
    #pragma unroll
    for (int q = 0; q < 4; ++q)
        #pragma unroll
        for (int i = 0; i < 4; ++i)
            #pragma unroll
            for (int j = 0; j < 2; ++j) acc[q][i][j] = (f32x4){0.f, 0.f, 0.f, 0.f};

    f16x8 af[2][4][2];     // [MQ][mf][kh]
    f16x8 bf1[2][2];       // q1 B-frags (re-read every half-iter)
    f16x8 bf0A[2][2];      // q0 B-frags, buffer-0 ping
    f16x8 bf0B[2][2];      // q0 B-frags, buffer-1 pong

    // Prologue: stage buf0<-k0 (8 loads), buf1<-k1 (8 loads); wait buf0 only.
    c2_stage_A(As, 0, 0, h1p, y, 0, t, cg);
    c2_stage_A(As, 0, 1, h1p, y, 0, t, cg);
    c2_stage_B(Bs, 0, 0, B2w, n0, 0, t, cg);
    c2_stage_B(Bs, 0, 1, B2w, n0, 0, t, cg);
    c2_stage_A(As, 1, 0, h1p, y, 1, t, cg);
    c2_stage_A(As, 1, 1, h1p, y, 1, t, cg);
    c2_stage_B(Bs, 1, 0, B2w, n0, 1, t, cg);
    c2_stage_B(Bs, 1, 1, B2w, n0, 1, t, cg);
    VMC(8);
    SBAR; SB0;
    RDBX(bf0A, 0, 0); SB0;
    RDA(0, 0);

    // Steady: 53 iterations (compute kt 0..105; stage up to kt 107).
    for (int i = 0; i < 53; ++i) {
        const int k2 = 2 * i + 2;
        const int k3 = 2 * i + 3;
        // ph1 (q00 buf0)
        RDBX(bf1, 1, 0);
        LGKM(4); SB0;
        MMA16X(0, 0, bf0A);
        SBAR;
        // ph2 (q01 buf0): stage A0h0,B0h0 <- k2
        c2_stage_A(As, 0, 0, h1p, y, k2, t, cg);
        c2_stage_B(Bs, 0, 0, B2w, n0, k2, t, cg);
        RDA(1, 0);
        LGKM(8); SB0;
        MMA16X(0, 1, bf1);
        SBAR;
        // ph3 (q11 buf0)
        LGKM(0); SB0;
        MMA16X(1, 1, bf1);
        SBAR;
        // ph4 (q10 buf0): stage A0h1,B0h1 <- k2; prefetch buf1 q0 frags PRE-MFMA
        c2_stage_A(As, 0, 1, h1p, y, k2, t, cg);
        c2_stage_B(Bs, 0, 1, B2w, n0, k2, t, cg);
        VMC(8);
        SBAR; SB0;
        RDA(0, 1);
        RDBX(bf0B, 0, 1); SB0;
        MMA16X(1, 0, bf0A);
        // (no barrier: ph6's stage is ordered behind ph5's LGKM+SBAR)
        // ph5 (q00 buf1)
        RDBX(bf1, 1, 1);
        LGKM(4); SB0;
        MMA16X(0, 0, bf0B);
        SBAR;
        // ph6 (q01 buf1): stage A1h0,B1h0 <- k3
        c2_stage_A(As, 1, 0, h1p, y, k3, t, cg);
        c2_stage_B(Bs, 1, 0, B2w, n0, k3, t, cg);
        RDA(1, 1);
        LGKM(8); SB0;
        MMA16X(0, 1, bf1);
        SBAR;
        // ph7 (q11 buf1)
        LGKM(0); SB0;
        MMA16X(1, 1, bf1);
        SBAR;
        // ph8 (q10 buf1): stage A1h1,B1h1 <- k3; prefetch buf0 q0 frags PRE-MFMA
        c2_stage_A(As, 1, 1, h1p, y, k3, t, cg);
        c2_stage_B(Bs, 1, 1, B2w, n0, k3, t, cg);
        VMC(8);
        SBAR; SB0;
        RDA(0, 0);
        RDBX(bf0A, 0, 0); SB0;
        MMA16X(1, 0, bf0B);
    }
    // Tail: kt 106 (buf0), 107 (buf1); no stages, drain once.
    {
        RDBX(bf1, 1, 0);
        LGKM(4); SB0;
        MMA16X(0, 0, bf0A);
        SBAR;
        RDA(1, 0);
        LGKM(8); SB0;
        MMA16X(0, 1, bf1);
        SBAR;
        LGKM(0); SB0;
        MMA16X(1, 1, bf1);
        SBAR;
        VMC(0);
        SBAR; SB0;
        RDA(0, 1);
        RDBX(bf0B, 0, 1); SB0;
        MMA16X(1, 0, bf0A);
        RDBX(bf1, 1, 1);
        LGKM(4); SB0;
        MMA16X(0, 0, bf0B);
        SBAR;
        RDA(1, 1);
        LGKM(8); SB0;
        MMA16X(0, 1, bf1);
        SBAR;
        LGKM(0); SB0;
        MMA16X(1, 1, bf1);
        SBAR;
        MMA16X(1, 0, bf0B);
    }

    // Epilogue: bias + leaky, write NHWC fp16.
    #pragma unroll
    for (int q = 0; q < 4; ++q) {
        const int mq = q >> 1, nq = q & 1;
        #pragma unroll
        for (int nf = 0; nf < 2; ++nf) {
            const int col = n0 + nq * 128 + wn * 32 + nf * 16 + ar;
            const float bias = b2[col];
            #pragma unroll
            for (int mf = 0; mf < 4; ++mf) {
                const int row = m0 + mq * 128 + wm * 64 + mf * 16 + kc * 4;
                half_t* op = h2 + (size_t)row * 768 + col;
                #pragma unroll
                for (int r4 = 0; r4 < 4; ++r4)
                    op[(size_t)r4 * 768] = (half_t)leaky(acc[q][mf][nf][r4] + bias);
            }
        }
    }
}

// ---------------------------------------------------------------------------
// conv3: 1x1 768->192 + leaky. GEMM M=65536 (one batch), N=192, K=768.
// ---------------------------------------------------------------------------
__global__ __launch_bounds__(256, 2)
void conv3_kernel(const half_t* __restrict__ h2, const half_t* __restrict__ B3w,
                  const float* __restrict__ b3, float* __restrict__ out, int batch)
{
    __shared__ half_t As[128 * 64];
    __shared__ half_t Bs[192 * 64];
    const int t = threadIdx.x;
    const int lane = t & 63;
    const int w = t >> 6;
    const int m0 = blockIdx.x * 128;
    const int wm = (w >> 1) * 64;
    const int wn = (w & 1) * 96;
    const int rbase = t >> 3;
    const int g = (t & 7) ^ (rbase & 7);
    const int ar = lane & 15, kc = lane >> 4;

    f32x4 acc[4][6];
    #pragma unroll
    for (int i = 0; i < 4; ++i)
        #pragma unroll
        for (int j = 0; j < 6; ++j) acc[i][j] = (f32x4){0.f, 0.f, 0.f, 0.f};

    for (int s = 0; s < 12; ++s) {
        const int k0 = s * 64;
        const half_t* ga = h2 + (size_t)(m0 + rbase) * 768 + k0 + g * 8;
        const half_t* gb = B3w + (size_t)rbase * 768 + k0 + g * 8;
        half_t* la = As + t * 8;
        half_t* lb = Bs + t * 8;
        #pragma unroll
        for (int i = 0; i < 4; ++i) stage16(ga + (size_t)32 * i * 768, la + 2048 * i);
        #pragma unroll
        for (int i = 0; i < 6; ++i) stage16(gb + (size_t)32 * i * 768, lb + 2048 * i);
        __syncthreads();
        #pragma unroll
        for (int kh = 0; kh < 2; ++kh) {
            f16x8 af[4], bfr[6];
            const int c = kh * 4 + kc;
            #pragma unroll
            for (int mf = 0; mf < 4; ++mf) {
                int r = wm + mf * 16 + ar;
                af[mf] = *(const f16x8*)&As[(r * 8 + (c ^ (r & 7))) * 8];
            }
            #pragma unroll
            for (int nf = 0; nf < 6; ++nf) {
                int r = wn + nf * 16 + ar;
                bfr[nf] = *(const f16x8*)&Bs[(r * 8 + (c ^ (r & 7))) * 8];
            }
            #pragma unroll
            for (int mf = 0; mf < 4; ++mf)
                #pragma unroll
                for (int nf = 0; nf < 6; ++nf)
                    acc[mf][nf] = __builtin_amdgcn_mfma_f32_16x16x32_f16(af[mf], bfr[nf], acc[mf][nf], 0, 0, 0);
        }
        __syncthreads();
    }

    #pragma unroll
    for (int nf = 0; nf < 6; ++nf) {
        int n = wn + nf * 16 + ar;
        float bias = b3[n];
        float* op = out + ((size_t)batch * 192 + n) * 65536 + m0;
        #pragma unroll
        for (int mf = 0; mf < 4; ++mf) {
            int local = wm + mf * 16 + kc * 4;
            f32x4 v;
            #pragma unroll
            for (int r4 = 0; r4 < 4; ++r4) v[r4] = leaky(acc[mf][nf][r4] + bias);
            *(f32x4*)(op + local) = v;
        }
    }
}

// ---------------------------------------------------------------------------
extern "C" void kernel_launch(void* const* d_in, const int* in_sizes, int n_in,
                              void* d_out, int out_size, void* d_ws, size_t ws_size,
                              hipStream_t stream)
{
    const float* x  = (const float*)d_in[0];
    const float* Wq = (const float*)d_in[1];
    const float* bq = (const float*)d_in[2];
    const float* Wk = (const float*)d_in[3];
    const float* bk = (const float*)d_in[4];
    const float* Wv = (const float*)d_in[5];
    const float* bv = (const float*)d_in[6];
    const float* Wo = (const float*)d_in[7];
    const float* bo = (const float*)d_in[8];
    const float* W1 = (const float*)d_in[9];
    const float* b1 = (const float*)d_in[10];
    const float* W2 = (const float*)d_in[11];
    const float* b2 = (const float*)d_in[12];
    const float* W3 = (const float*)d_in[13];
    const float* b3 = (const float*)d_in[14];

    char* ws = (char*)d_ws;
    const size_t OFF_B1   = 0;
    const size_t OFF_B3   = 294912;
    const size_t OFF_B2   = 589824;
    const size_t OFF_FEAT = 11206656;
    const size_t OFF_H1P  = 111869952;
    const size_t OFF_H2   = 214124544;
    const size_t WS_NEED  = 314787840;
    if (ws_size < WS_NEED) return;

    half_t* B1w   = (half_t*)(ws + OFF_B1);
    half_t* B3w   = (half_t*)(ws + OFF_B3);
    half_t* B2w   = (half_t*)(ws + OFF_B2);
    half_t* featN = (half_t*)(ws + OFF_FEAT);
    half_t* h1p   = (half_t*)(ws + OFF_H1P);
    half_t* h2    = (half_t*)(ws + OFF_H2);

    hipMemsetAsync(h1p, 0, 102254592, stream);
    prep_kernel<<<21888, 256, 0, stream>>>(W1, W2, W3, B1w, B2w, B3w);
    attn_kernel<<<4096, 256, 0, stream>>>(x, Wq, bq, Wk, bk, Wv, bv, Wo, bo, featN);

    for (int b = 0; b < 4; ++b) {
        conv1_kernel<<<dim3(512, 6), 256, 0, stream>>>(featN, B1w, b1, h1p, b);
        conv2_kernel<<<768, 512, 0, stream>>>(h1p, B2w, b2, h2);
        conv3_kernel<<<dim3(512, 1), 256, 0, stream>>>(h2, B3w, b3, (float*)d_out, b);
    }
}

// Round 7
// 2986.810 us; speedup vs baseline: 1.1414x; 1.0224x over previous
//
#include <hip/hip_runtime.h>
#include <stdint.h>
#include <math.h>

typedef _Float16 half_t;
typedef _Float16 f16x8 __attribute__((ext_vector_type(8)));
typedef float f32x4 __attribute__((ext_vector_type(4)));

#define SLOPE 0.01f

__device__ inline float leaky(float v) { return v > 0.f ? v : SLOPE * v; }

__device__ inline void stage16(const half_t* g, half_t* l) {
    __builtin_amdgcn_global_load_lds(
        (const __attribute__((address_space(1))) unsigned int*)g,
        (__attribute__((address_space(3))) unsigned int*)l, 16, 0, 0);
}

__device__ inline float softplusf(float v) {
    return v > 20.f ? v : log1pf(expf(v));
}

// ---------------------------------------------------------------------------
// Weight prep. B2w is K-MAJOR: B2w[kstep][oc][icw], kstep = tap*12 + ic/64,
// so one K-step's B slab (768 oc x 64 ic = 96 KB) is contiguous -> L2-resident
// across all 3 n-panels of roughly-synchronized blocks.
// ---------------------------------------------------------------------------
__global__ void prep_kernel(const float* __restrict__ W1, const float* __restrict__ W2,
                            const float* __restrict__ W3,
                            half_t* __restrict__ B1w, half_t* __restrict__ B2w,
                            half_t* __restrict__ B3w)
{
    const unsigned idx = blockIdx.x * 256u + threadIdx.x;
    const unsigned n2 = 768u * 6912u;                 // 5,308,416
    if (idx < n2) {
        unsigned ks  = idx / 49152u;                  // 0..107
        unsigned r   = idx - ks * 49152u;
        unsigned oc  = r >> 6;
        unsigned icw = r & 63u;
        unsigned tap = ks / 12u;
        unsigned icc = ks - tap * 12u;
        unsigned ic  = icc * 64u + icw;
        unsigned ky = tap / 3u, kx = tap - ky * 3u;
        B2w[idx] = (half_t)W2[(((size_t)oc * 768u + ic) * 3u + ky) * 3u + kx];
    } else if (idx < n2 + 147456u) {
        unsigned i = idx - n2;
        B1w[i] = (half_t)W1[i];                       // W1 flat is already (oc,ic)
    } else if (idx < n2 + 294912u) {
        unsigned i = idx - n2 - 147456u;
        B3w[i] = (half_t)W3[i];                       // W3 flat is already (oc,ic)
    }
}

// ---------------------------------------------------------------------------
// Per-window linear attention. One block per window. Writes feat NHWC fp16.
// ---------------------------------------------------------------------------
__global__ __launch_bounds__(256, 2)
void attn_kernel(const float* __restrict__ x,
                 const float* __restrict__ Wq, const float* __restrict__ bq,
                 const float* __restrict__ Wk, const float* __restrict__ bk,
                 const float* __restrict__ Wv, const float* __restrict__ bv,
                 const float* __restrict__ Wo, const float* __restrict__ bo,
                 half_t* __restrict__ featN)
{
    __shared__ half_t xls[192 * 65];
    __shared__ float wqL[512], wkL[512], wvL[512], woL[512];
    __shared__ float bqL[8], bkL[8], bvL[8], boL[64];
    __shared__ float kls[192 * 9], vls[192 * 9];
    __shared__ float sls[64];

    const int t = threadIdx.x;
    const int blk = blockIdx.x;
    const int b = blk >> 10;
    const int n = blk & 1023;
    const int wi = n >> 5, wj = n & 31;

    for (int i = t; i < 512; i += 256) {
        wqL[i] = Wq[i]; wkL[i] = Wk[i]; wvL[i] = Wv[i]; woL[i] = Wo[i];
    }
    if (t < 8)  { bqL[t] = bq[t]; bkL[t] = bk[t]; bvL[t] = bv[t]; }
    if (t < 64) boL[t] = bo[t];

    #pragma unroll
    for (int i = 0; i < 6; ++i) {
        int idx = t + i * 256;                 // 0..1535 = (c,py)
        int c = idx >> 3, py = idx & 7;
        const float* src = x + (((size_t)b * 192 + c) * 256 + (wi * 8 + py)) * 256 + wj * 8;
        float4 v0 = *(const float4*)src;
        float4 v1 = *(const float4*)(src + 4);
        half_t* dst = &xls[c * 65 + py * 8];
        dst[0] = (half_t)v0.x; dst[1] = (half_t)v0.y; dst[2] = (half_t)v0.z; dst[3] = (half_t)v0.w;
        dst[4] = (half_t)v1.x; dst[5] = (half_t)v1.y; dst[6] = (half_t)v1.z; dst[7] = (half_t)v1.w;
    }
    __syncthreads();

    float qf[8], kf[8], vf[8];
    if (t < 192) {
        #pragma unroll
        for (int d = 0; d < 8; ++d) { qf[d] = bqL[d]; kf[d] = bkL[d]; vf[d] = bvL[d]; }
        const half_t* xr = &xls[t * 65];
        for (int p = 0; p < 64; ++p) {
            float xv = (float)xr[p];
            const float* wqp = &wqL[p * 8];
            const float* wkp = &wkL[p * 8];
            const float* wvp = &wvL[p * 8];
            #pragma unroll
            for (int d = 0; d < 8; ++d) {
                qf[d] += xv * wqp[d];
                kf[d] += xv * wkp[d];
                vf[d] += xv * wvp[d];
            }
        }
        #pragma unroll
        for (int d = 0; d < 8; ++d) {
            qf[d] = softplusf(qf[d]);
            kf[d] = softplusf(kf[d]);
            kls[t * 9 + d] = kf[d];
            vls[t * 9 + d] = vf[d];
        }
    }
    __syncthreads();
    if (t < 64) {
        int e = t >> 3, dd = t & 7;
        float s = 0.f;
        for (int c = 0; c < 192; ++c) s += kls[c * 9 + e] * vls[c * 9 + dd];
        sls[t] = s;
    }
    __syncthreads();
    if (t < 192) {
        float rf[8];
        #pragma unroll
        for (int d = 0; d < 8; ++d) {
            float s = 0.f;
            #pragma unroll
            for (int e = 0; e < 8; ++e) s += qf[e] * sls[e * 8 + d];
            rf[d] = s;
        }
        half_t* xr = &xls[t * 65];
        for (int p = 0; p < 64; ++p) {
            float a = boL[p];
            #pragma unroll
            for (int d = 0; d < 8; ++d) a += rf[d] * woL[d * 64 + p];
            xr[p] = (half_t)((float)xr[p] + a);
        }
    }
    __syncthreads();
    half_t* dst = featN + ((size_t)b * 65536 + (size_t)n * 64) * 192;
    for (int i = 0; i < 48; ++i) {
        int idx = t + i * 256;                 // 0..12287 = p*192 + c
        int p = idx / 192, c = idx - p * 192;
        dst[idx] = xls[c * 65 + p];
    }
}

// ---------------------------------------------------------------------------
// conv1: 1x1 192->768 + leaky. GEMM M=65536 (one batch), N=768, K=192.
// ---------------------------------------------------------------------------
__global__ __launch_bounds__(256, 2)
void conv1_kernel(const half_t* __restrict__ featN, const half_t* __restrict__ B1w,
                  const float* __restrict__ b1, half_t* __restrict__ h1p, int batch)
{
    __shared__ half_t As[128 * 64];
    __shared__ half_t Bs[128 * 64];
    const int t = threadIdx.x;
    const int lane = t & 63;
    const int w = t >> 6;
    const int m0 = blockIdx.x * 128;
    const int n0 = blockIdx.y * 128;
    const int wm = (w >> 1) * 64, wn = (w & 1) * 64;
    const int rbase = t >> 3;
    const int g = (t & 7) ^ (rbase & 7);
    const int ar = lane & 15, kc = lane >> 4;

    f32x4 acc[4][4];
    #pragma unroll
    for (int i = 0; i < 4; ++i)
        #pragma unroll
        for (int j = 0; j < 4; ++j) acc[i][j] = (f32x4){0.f, 0.f, 0.f, 0.f};

    const size_t mb = (size_t)batch * 65536 + m0;

    for (int s = 0; s < 3; ++s) {
        const int k0 = s * 64;
        const half_t* ga = featN + (mb + rbase) * 192 + k0 + g * 8;
        const half_t* gb = B1w + (size_t)(n0 + rbase) * 192 + k0 + g * 8;
        half_t* la = As + t * 8;
        half_t* lb = Bs + t * 8;
        #pragma unroll
        for (int i = 0; i < 4; ++i) {
            stage16(ga + (size_t)32 * i * 192, la + 2048 * i);
            stage16(gb + (size_t)32 * i * 192, lb + 2048 * i);
        }
        __syncthreads();
        #pragma unroll
        for (int kh = 0; kh < 2; ++kh) {
            f16x8 af[4], bfr[4];
            const int c = kh * 4 + kc;
            #pragma unroll
            for (int mf = 0; mf < 4; ++mf) {
                int r = wm + mf * 16 + ar;
                af[mf] = *(const f16x8*)&As[(r * 8 + (c ^ (r & 7))) * 8];
            }
            #pragma unroll
            for (int nf = 0; nf < 4; ++nf) {
                int r = wn + nf * 16 + ar;
                bfr[nf] = *(const f16x8*)&Bs[(r * 8 + (c ^ (r & 7))) * 8];
            }
            #pragma unroll
            for (int mf = 0; mf < 4; ++mf)
                #pragma unroll
                for (int nf = 0; nf < 4; ++nf)
                    acc[mf][nf] = __builtin_amdgcn_mfma_f32_16x16x32_f16(af[mf], bfr[nf], acc[mf][nf], 0, 0, 0);
        }
        __syncthreads();
    }

    const int y = m0 >> 8, x0 = m0 & 255;
    half_t* outrow = h1p + ((size_t)(y + 1) * 258 + (x0 + 1)) * 768;
    #pragma unroll
    for (int nf = 0; nf < 4; ++nf) {
        int n = n0 + wn + nf * 16 + ar;
        float bias = b1[n];
        #pragma unroll
        for (int mf = 0; mf < 4; ++mf) {
            #pragma unroll
            for (int r4 = 0; r4 < 4; ++r4) {
                int local = wm + mf * 16 + kc * 4 + r4;
                outrow[(size_t)local * 768 + n] = (half_t)leaky(acc[mf][nf][r4] + bias);
            }
        }
    }
}

// ---------------------------------------------------------------------------
// conv2 v7 = EXACT v4 schedule (best measured: 670us/50.6%) + k-major B2w.
// 3x3 SAME 768->768 + leaky, implicit GEMM, 256x256 tile, BK=64, 8-phase,
// read-ahead with counted lgkm (12/8/0), post-MFMA cross-buffer reads at
// ph4/ph8 after VMC(8)+barrier. Grid: nt innermost + XCD-chunked mtile.
// ---------------------------------------------------------------------------
__device__ __forceinline__ void c2_stage_A(half_t* As, int buf, int h,
    const half_t* __restrict__ h1p, int y, int kstep, int t, int cg)
{
    const int tap = kstep / 12, icc = kstep - tap * 12;
    const int ky = tap / 3, kx = tap - ky * 3;
    const int row0 = t >> 3;
    const half_t* g = h1p + ((size_t)(y + ky) * 258 + (kx + h * 128 + row0)) * 768
                      + icc * 64 + cg;
    half_t* l = As + (buf * 2 + h) * 8192 + t * 8;
    stage16(g, l);
    stage16(g + (size_t)64 * 768, l + 4096);
}

__device__ __forceinline__ void c2_stage_B(half_t* Bs, int buf, int h,
    const half_t* __restrict__ B2w, int n0, int kstep, int t, int cg)
{
    // k-major B2w: [kstep][oc][icw]; row stride 64, slab stride 49152.
    const int row0 = t >> 3;
    const half_t* g = B2w + (size_t)kstep * 49152
                      + (size_t)(n0 + h * 128 + row0) * 64 + cg;
    half_t* l = Bs + (buf * 2 + h) * 8192 + t * 8;
    stage16(g, l);
    stage16(g + (size_t)64 * 64, l + 4096);
}

#define SBAR __builtin_amdgcn_s_barrier()
#define SB0  __builtin_amdgcn_sched_barrier(0)
#define LGKM(N) asm volatile("s_waitcnt lgkmcnt(" #N ")" ::: "memory")
#define VMC(N)  asm volatile("s_waitcnt vmcnt(" #N ")" ::: "memory")

// 8 ds_read_b128 into af[MQ] (frags for both kh of quadrant row-half MQ)
#define RDA(MQ, BUF)                                                             \
  _Pragma("unroll")                                                              \
  for (int mf = 0; mf < 4; ++mf)                                                 \
    _Pragma("unroll")                                                            \
    for (int kh = 0; kh < 2; ++kh) {                                             \
      const int lr = wm * 64 + mf * 16 + ar;                                     \
      const int ch = (kh * 4 + kc) ^ (lr & 7);                                   \
      af[MQ][mf][kh] = *(const f16x8*)&As[((BUF)*2 + (MQ))*8192 + lr*64 + ch*8]; \
    }

// 4 ds_read_b128 into bf[NQ]
#define RDB(NQ, BUF)                                                             \
  _Pragma("unroll")                                                              \
  for (int nf = 0; nf < 2; ++nf)                                                 \
    _Pragma("unroll")                                                            \
    for (int kh = 0; kh < 2; ++kh) {                                             \
      const int lc = wn * 32 + nf * 16 + ar;                                     \
      const int ch = (kh * 4 + kc) ^ (lc & 7);                                   \
      bf[NQ][nf][kh] = *(const f16x8*)&Bs[((BUF)*2 + (NQ))*8192 + lc*64 + ch*8]; \
    }

#define MMA16(MQ, NQ)                                                            \
  {                                                                              \
    __builtin_amdgcn_s_setprio(1);                                               \
    _Pragma("unroll")                                                            \
    for (int kh = 0; kh < 2; ++kh)                                               \
      _Pragma("unroll")                                                          \
      for (int mf = 0; mf < 4; ++mf)                                             \
        _Pragma("unroll")                                                        \
        for (int nf = 0; nf < 2; ++nf)                                           \
          acc[(MQ)*2+(NQ)][mf][nf] = __builtin_amdgcn_mfma_f32_16x16x32_f16(     \
              af[MQ][mf][kh], bf[NQ][nf][kh], acc[(MQ)*2+(NQ)][mf][nf], 0, 0, 0);\
    __builtin_amdgcn_s_setprio(0);                                               \
  }

__global__ __launch_bounds__(512, 2)
void conv2_kernel(const half_t* __restrict__ h1p, const half_t* __restrict__ B2w,
                  const float* __restrict__ b2, half_t* __restrict__ h2)
{
    __shared__ half_t As[4 * 8192];    // [buf][half][128][64] f16 = 64 KiB
    __shared__ half_t Bs[4 * 8192];

    const int t = threadIdx.x;
    const int lane = t & 63;
    const int w = t >> 6;
    const int wm = w >> 2, wn = w & 3;            // 2x4 wave grid inside a quadrant
    const int ar = lane & 15, kc = lane >> 4;
    const int cg = (((t & 7) ^ ((t >> 3) & 7)) << 3);  // pre-swizzled source chunk

    // v4 grid: nt innermost + XCD-chunked mtile bands.
    const int bid = blockIdx.x;
    const int xcd = bid & 7, sid = bid >> 3;      // 96 blocks per XCD
    const int wg = xcd * 96 + sid;                // 768 = 8 XCD * 96
    const int mtile = wg / 3;
    const int nt = wg - mtile * 3;
    const int y = mtile;
    const int m0 = mtile * 256;
    const int n0 = nt * 256;

    f32x4 acc[4][4][2];
    #pragma unroll
    for (int q = 0; q < 4; ++q)
        #pragma unroll
        for (int i = 0; i < 4; ++i)
            #pragma unroll
            for (int j = 0; j < 2; ++j) acc[q][i][j] = (f32x4){0.f, 0.f, 0.f, 0.f};

    f16x8 af[2][4][2];   // [MQ][mf][kh]
    f16x8 bf[2][2][2];   // [NQ][nf][kh]

    // Prologue: stage buf0<-k0, buf1<-k1 fully; drain; issue boundary reads.
    c2_stage_A(As, 0, 0, h1p, y, 0, t, cg);
    c2_stage_A(As, 0, 1, h1p, y, 0, t, cg);
    c2_stage_B(Bs, 0, 0, B2w, n0, 0, t, cg);
    c2_stage_B(Bs, 0, 1, B2w, n0, 0, t, cg);
    c2_stage_A(As, 1, 0, h1p, y, 1, t, cg);
    c2_stage_A(As, 1, 1, h1p, y, 1, t, cg);
    c2_stage_B(Bs, 1, 0, B2w, n0, 1, t, cg);
    c2_stage_B(Bs, 1, 1, B2w, n0, 1, t, cg);
    VMC(0);
    SBAR; SB0;
    RDB(0, 0); SB0;
    RDA(0, 0);

    // Steady: 53 iterations (compute kt 0..105; stage up to kt 107).
    for (int i = 0; i < 53; ++i) {
        const int k2 = 2 * i + 2;
        const int k3 = 2 * i + 3;
        // ph1 (q00 buf0): read-ahead bf1,af1 of buf0.
        RDB(1, 0); SB0;
        RDA(1, 0);
        LGKM(12); SB0;
        MMA16(0, 0);
        SBAR;
        // ph2 (q01 buf0): stage A0h0,B0h0 <- k2.
        c2_stage_A(As, 0, 0, h1p, y, k2, t, cg);
        c2_stage_B(Bs, 0, 0, B2w, n0, k2, t, cg);
        LGKM(8); SB0;
        MMA16(0, 1);
        SBAR;
        // ph3 (q11 buf0).
        LGKM(0); SB0;
        MMA16(1, 1);
        SBAR;
        // ph4 (q10 buf0): stage A0h1,B0h1 <- k2; vmcnt(8); post-reads buf1.
        c2_stage_A(As, 0, 1, h1p, y, k2, t, cg);
        c2_stage_B(Bs, 0, 1, B2w, n0, k2, t, cg);
        VMC(8);
        SBAR; SB0;
        MMA16(1, 0);
        SB0;
        RDB(0, 1); SB0;
        RDA(0, 1);
        SBAR;
        // ph5 (q00 buf1): read-ahead bf1,af1 of buf1.
        RDB(1, 1); SB0;
        RDA(1, 1);
        LGKM(12); SB0;
        MMA16(0, 0);
        SBAR;
        // ph6 (q01 buf1): stage A1h0,B1h0 <- k3.
        c2_stage_A(As, 1, 0, h1p, y, k3, t, cg);
        c2_stage_B(Bs, 1, 0, B2w, n0, k3, t, cg);
        LGKM(8); SB0;
        MMA16(0, 1);
        SBAR;
        // ph7 (q11 buf1).
        LGKM(0); SB0;
        MMA16(1, 1);
        SBAR;
        // ph8 (q10 buf1): stage A1h1,B1h1 <- k3; vmcnt(8); post-reads buf0 next.
        c2_stage_A(As, 1, 1, h1p, y, k3, t, cg);
        c2_stage_B(Bs, 1, 1, B2w, n0, k3, t, cg);
        VMC(8);
        SBAR; SB0;
        MMA16(1, 0);
        SB0;
        RDB(0, 0); SB0;
        RDA(0, 0);
        SBAR;
    }
    // Tail (kt 106,107): no stages, no next-buffer reads.
    {
        // ph1
        RDB(1, 0); SB0;
        RDA(1, 0);
        LGKM(12); SB0;
        MMA16(0, 0);
        SBAR;
        // ph2
        LGKM(8); SB0;
        MMA16(0, 1);
        SBAR;
        // ph3
        LGKM(0); SB0;
        MMA16(1, 1);
        SBAR;
        // ph4: drain all remaining stages (prev ph6/ph8), then buf1 reads.
        VMC(0);
        SBAR; SB0;
        MMA16(1, 0);
        SB0;
        RDB(0, 1); SB0;
        RDA(0, 1);
        SBAR;
        // ph5
        RDB(1, 1); SB0;
        RDA(1, 1);
        LGKM(12); SB0;
        MMA16(0, 0);
        SBAR;
        // ph6
        LGKM(8); SB0;
        MMA16(0, 1);
        SBAR;
        // ph7
        LGKM(0); SB0;
        MMA16(1, 1);
        SBAR;
        // ph8
        MMA16(1, 0);
    }

    // Epilogue: bias + leaky, write NHWC fp16.
    #pragma unroll
    for (int q = 0; q < 4; ++q) {
        const int mq = q >> 1, nq = q & 1;
        #pragma unroll
        for (int nf = 0; nf < 2; ++nf) {
            const int col = n0 + nq * 128 + wn * 32 + nf * 16 + ar;
            const float bias = b2[col];
            #pragma unroll
            for (int mf = 0; mf < 4; ++mf) {
                const int row = m0 + mq * 128 + wm * 64 + mf * 16 + kc * 4;
                half_t* op = h2 + (size_t)row * 768 + col;
                #pragma unroll
                for (int r4 = 0; r4 < 4; ++r4)
                    op[(size_t)r4 * 768] = (half_t)leaky(acc[q][mf][nf][r4] + bias);
            }
        }
    }
}

// ---------------------------------------------------------------------------
// conv3: 1x1 768->192 + leaky. GEMM M=65536 (one batch), N=192, K=768.
// ---------------------------------------------------------------------------
__global__ __launch_bounds__(256, 2)
void conv3_kernel(const half_t* __restrict__ h2, const half_t* __restrict__ B3w,
                  const float* __restrict__ b3, float* __restrict__ out, int batch)
{
    __shared__ half_t As[128 * 64];
    __shared__ half_t Bs[192 * 64];
    const int t = threadIdx.x;
    const int lane = t & 63;
    const int w = t >> 6;
    const int m0 = blockIdx.x * 128;
    const int wm = (w >> 1) * 64;
    const int wn = (w & 1) * 96;
    const int rbase = t >> 3;
    const int g = (t & 7) ^ (rbase & 7);
    const int ar = lane & 15, kc = lane >> 4;

    f32x4 acc[4][6];
    #pragma unroll
    for (int i = 0; i < 4; ++i)
        #pragma unroll
        for (int j = 0; j < 6; ++j) acc[i][j] = (f32x4){0.f, 0.f, 0.f, 0.f};

    for (int s = 0; s < 12; ++s) {
        const int k0 = s * 64;
        const half_t* ga = h2 + (size_t)(m0 + rbase) * 768 + k0 + g * 8;
        const half_t* gb = B3w + (size_t)rbase * 768 + k0 + g * 8;
        half_t* la = As + t * 8;
        half_t* lb = Bs + t * 8;
        #pragma unroll
        for (int i = 0; i < 4; ++i) stage16(ga + (size_t)32 * i * 768, la + 2048 * i);
        #pragma unroll
        for (int i = 0; i < 6; ++i) stage16(gb + (size_t)32 * i * 768, lb + 2048 * i);
        __syncthreads();
        #pragma unroll
        for (int kh = 0; kh < 2; ++kh) {
            f16x8 af[4], bfr[6];
            const int c = kh * 4 + kc;
            #pragma unroll
            for (int mf = 0; mf < 4; ++mf) {
                int r = wm + mf * 16 + ar;
                af[mf] = *(const f16x8*)&As[(r * 8 + (c ^ (r & 7))) * 8];
            }
            #pragma unroll
            for (int nf = 0; nf < 6; ++nf) {
                int r = wn + nf * 16 + ar;
                bfr[nf] = *(const f16x8*)&Bs[(r * 8 + (c ^ (r & 7))) * 8];
            }
            #pragma unroll
            for (int mf = 0; mf < 4; ++mf)
                #pragma unroll
                for (int nf = 0; nf < 6; ++nf)
                    acc[mf][nf] = __builtin_amdgcn_mfma_f32_16x16x32_f16(af[mf], bfr[nf], acc[mf][nf], 0, 0, 0);
        }
        __syncthreads();
    }

    #pragma unroll
    for (int nf = 0; nf < 6; ++nf) {
        int n = wn + nf * 16 + ar;
        float bias = b3[n];
        float* op = out + ((size_t)batch * 192 + n) * 65536 + m0;
        #pragma unroll
        for (int mf = 0; mf < 4; ++mf) {
            int local = wm + mf * 16 + kc * 4;
            f32x4 v;
            #pragma unroll
            for (int r4 = 0; r4 < 4; ++r4) v[r4] = leaky(acc[mf][nf][r4] + bias);
            *(f32x4*)(op + local) = v;
        }
    }
}

// ---------------------------------------------------------------------------
extern "C" void kernel_launch(void* const* d_in, const int* in_sizes, int n_in,
                              void* d_out, int out_size, void* d_ws, size_t ws_size,
                              hipStream_t stream)
{
    const float* x  = (const float*)d_in[0];
    const float* Wq = (const float*)d_in[1];
    const float* bq = (const float*)d_in[2];
    const float* Wk = (const float*)d_in[3];
    const float* bk = (const float*)d_in[4];
    const float* Wv = (const float*)d_in[5];
    const float* bv = (const float*)d_in[6];
    const float* Wo = (const float*)d_in[7];
    const float* bo = (const float*)d_in[8];
    const float* W1 = (const float*)d_in[9];
    const float* b1 = (const float*)d_in[10];
    const float* W2 = (const float*)d_in[11];
    const float* b2 = (const float*)d_in[12];
    const float* W3 = (const float*)d_in[13];
    const float* b3 = (const float*)d_in[14];

    char* ws = (char*)d_ws;
    const size_t OFF_B1   = 0;
    const size_t OFF_B3   = 294912;
    const size_t OFF_B2   = 589824;
    const size_t OFF_FEAT = 11206656;
    const size_t OFF_H1P  = 111869952;
    const size_t OFF_H2   = 214124544;
    const size_t WS_NEED  = 314787840;
    if (ws_size < WS_NEED) return;

    half_t* B1w   = (half_t*)(ws + OFF_B1);
    half_t* B3w   = (half_t*)(ws + OFF_B3);
    half_t* B2w   = (half_t*)(ws + OFF_B2);
    half_t* featN = (half_t*)(ws + OFF_FEAT);
    half_t* h1p   = (half_t*)(ws + OFF_H1P);
    half_t* h2    = (half_t*)(ws + OFF_H2);

    hipMemsetAsync(h1p, 0, 102254592, stream);
    prep_kernel<<<21888, 256, 0, stream>>>(W1, W2, W3, B1w, B2w, B3w);
    attn_kernel<<<4096, 256, 0, stream>>>(x, Wq, bq, Wk, bk, Wv, bv, Wo, bo, featN);

    for (int b = 0; b < 4; ++b) {
        conv1_kernel<<<dim3(512, 6), 256, 0, stream>>>(featN, B1w, b1, h1p, b);
        conv2_kernel<<<768, 512, 0, stream>>>(h1p, B2w, b2, h2);
        conv3_kernel<<<dim3(512, 1), 256, 0, stream>>>(h2, B3w, b3, (float*)d_out, b);
    }
}